// Round 11
// baseline (436.147 us; speedup 1.0000x reference)
//
#include <hip/hip_runtime.h>
#include <hip/hip_bf16.h>

#define GN 8192
#define IN_DIM 512
#define ODIM 64
#define SLOPE 0.2f
#define JSPLIT 16
#define JCH (GN / JSPLIT)      // 512 cols per tile
#define LSTRIDE 68             // LDS mask row stride bytes (17 words -> conflict-free)
#define NTILE 2                // tiles per block (js0, js0+8; traversed descending)

typedef __attribute__((ext_vector_type(4))) float  f32x4;
typedef __attribute__((ext_vector_type(4))) int    i32x4;
typedef __attribute__((ext_vector_type(8))) short  bf16x8;
typedef __attribute__((ext_vector_type(4))) unsigned short u16x4;

static __device__ __forceinline__ float bf2f(unsigned short u) {
    return __uint_as_float(((unsigned)u) << 16);
}
static __device__ __forceinline__ unsigned short f2bf(float f) {
    union { float f; unsigned u; } c; c.f = f;
    unsigned b = c.u;
    return (unsigned short)((b + 0x7fffu + ((b >> 16) & 1u)) >> 16);  // RNE
}

// load 8 contiguous elements as bf16x8, from either wire dtype
static __device__ __forceinline__ bf16x8 load8(const void* p, size_t off, int f32) {
    if (f32) {
        f32x4 lo = *(const f32x4*)((const float*)p + off);
        f32x4 hi = *(const f32x4*)((const float*)p + off + 4);
        bf16x8 r;
        #pragma unroll
        for (int q = 0; q < 4; ++q) {
            r[q]     = (short)f2bf(lo[q]);
            r[4 + q] = (short)f2bf(hi[q]);
        }
        return r;
    }
    return *(const bf16x8*)((const ushort*)p + off);
}

// Kernel 1 (MFMA GEMM): Wh = x@W^T. Epilogue writes WhTp in B-operand-native
// layout (16B unit U(jblk,n) = Wh[jblk*8+0..7][n]); s, d, dmax, dflag; zero-
// inits accum/lsum (kernel boundary orders it before gat_attn's atomics).
extern "C" __global__ __launch_bounds__(256)
void gat_proj(const void* __restrict__ x_, const void* __restrict__ W_,
              const void* __restrict__ as_, const void* __restrict__ ad_,
              ushort* __restrict__ WhTp, float* __restrict__ s_arr,
              float* __restrict__ d_arr, int* __restrict__ dmax_bits,
              int* __restrict__ dflag, float* __restrict__ accum,
              float* __restrict__ lsum)
{
    {
        f32x4 z = {0.f, 0.f, 0.f, 0.f};
        f32x4* ap = (f32x4*)(accum + (size_t)blockIdx.x * 4096);
        #pragma unroll
        for (int k = 0; k < 4; ++k) ap[k * 256 + threadIdx.x] = z;
        if (threadIdx.x < 64) lsum[blockIdx.x * 64 + threadIdx.x] = 0.f;
    }
    const int wave = threadIdx.x >> 6;
    const int lane = threadIdx.x & 63;
    unsigned xw = ((const unsigned*)x_)[lane];
    unsigned ef = (xw >> 23) & 0xffu;
    unsigned long long vt = __ballot(ef > 60u && ef < 180u);
    const int f32 = (__popcll(vt) >= 32) ? 1 : 0;
    if (blockIdx.x == 0 && threadIdx.x == 0) *dflag = f32;

    const int quad = lane >> 4;
    const int lq   = lane & 15;
    const int i0   = blockIdx.x * 64 + wave * 16;

    f32x4 acc[4] = {{0,0,0,0},{0,0,0,0},{0,0,0,0},{0,0,0,0}};
    const size_t arow = (size_t)(i0 + lq) * IN_DIM;
    #pragma unroll 2
    for (int k0 = 0; k0 < IN_DIM; k0 += 32) {
        const int kk = k0 + quad * 8;
        bf16x8 a  = load8(x_, arow + kk, f32);
        bf16x8 b0 = load8(W_, (size_t)( 0 + lq) * IN_DIM + kk, f32);
        bf16x8 b1 = load8(W_, (size_t)(16 + lq) * IN_DIM + kk, f32);
        bf16x8 b2 = load8(W_, (size_t)(32 + lq) * IN_DIM + kk, f32);
        bf16x8 b3 = load8(W_, (size_t)(48 + lq) * IN_DIM + kk, f32);
        acc[0] = __builtin_amdgcn_mfma_f32_16x16x32_bf16(a, b0, acc[0], 0, 0, 0);
        acc[1] = __builtin_amdgcn_mfma_f32_16x16x32_bf16(a, b1, acc[1], 0, 0, 0);
        acc[2] = __builtin_amdgcn_mfma_f32_16x16x32_bf16(a, b2, acc[2], 0, 0, 0);
        acc[3] = __builtin_amdgcn_mfma_f32_16x16x32_bf16(a, b3, acc[3], 0, 0, 0);
    }
    float av_s[4], av_d[4];
    #pragma unroll
    for (int t = 0; t < 4; ++t) {
        const int n = t * 16 + lq;
        av_s[t] = f32 ? ((const float*)as_)[n] : bf2f(((const ushort*)as_)[n]);
        av_d[t] = f32 ? ((const float*)ad_)[n] : bf2f(((const ushort*)ad_)[n]);
    }
    #pragma unroll
    for (int t = 0; t < 4; ++t) {
        u16x4 pk;
        #pragma unroll
        for (int r = 0; r < 4; ++r) pk[r] = f2bf(acc[t][r]);
        const size_t hw = ((size_t)((i0 >> 3) + (quad >> 1)) * 64 + t * 16 + lq) * 8
                          + (quad & 1) * 4;
        *(u16x4*)(WhTp + hw) = pk;
    }
    float ps[4], pd[4];
    #pragma unroll
    for (int r = 0; r < 4; ++r) {
        float s = 0.f, d = 0.f;
        #pragma unroll
        for (int t = 0; t < 4; ++t) {
            s = fmaf(acc[t][r], av_s[t], s);
            d = fmaf(acc[t][r], av_d[t], d);
        }
        #pragma unroll
        for (int off = 1; off < 16; off <<= 1) {
            s += __shfl_xor(s, off);
            d += __shfl_xor(d, off);
        }
        ps[r] = s; pd[r] = d;
    }
    if (lq == 0) {
        float dmx = -1e30f;
        #pragma unroll
        for (int r = 0; r < 4; ++r) {
            s_arr[i0 + quad * 4 + r] = ps[r];
            d_arr[i0 + quad * 4 + r] = pd[r];
            dmx = fmaxf(dmx, pd[r]);
        }
        if (dmx > 0.f) atomicMax(dmax_bits, __float_as_int(dmx));
    }
}

// Kernel 2: fused attention = R10 structure + MORE TLP + DEEPER RING.
// 1024 blocks = 128 ib x 8 js0 with __launch_bounds__(256,3) (VGPR<=170,
// no spill at ~155 est.) -> 3 blocks/CU = 12 waves resident (R10 had 8).
// Ring 6 / pack-lag 5: each adj chunk gets ~5 iter-bodies (~1000-1250 cy)
// of cover vs ~900 cy HBM-miss latency (m126) - slack over R10's lag 4.
// Tiles js0+8, js0 traversed descending; ib reversed (L3 tail scavenge).
// Exp folded: w = expf(max(dj+k1, fma(0.2,dj,k2))); bf16 pack via cvt_pk.
extern "C" __global__ __launch_bounds__(256, 3)
void gat_attn(const int* __restrict__ adj, const ushort* __restrict__ WhTp,
              const float* __restrict__ s_arr, const float* __restrict__ d_arr,
              const int* __restrict__ dmax_bits,
              float* __restrict__ accum, float* __restrict__ lsum)
{
    __shared__ unsigned char mb[2][64 * LSTRIDE];
    const int b    = blockIdx.x;        // 0..1023
    const int ib   = 127 - (b & 127);   // reversed: high rows first
    const int js0  = b >> 7;            // 0..7
    const int wave = threadIdx.x >> 6;
    const int lane = threadIdx.x & 63;
    const int quad = lane >> 4;
    const int lq   = lane & 15;
    const int i0   = ib * 64;
    const int li   = wave * 16 + lq;
    const int i    = i0 + li;
    const float dmax = __int_as_float(*dmax_bits);
    const float si = s_arr[i];
    const float tbv = si + dmax;
    const float mi = fmaxf(tbv, SLOPE * tbv);   // row-logit upper bound
    const float k1 = si - mi;                   // arg = max(dj+k1, 0.2dj+k2)
    const float k2 = SLOPE * si - mi;

    const size_t adjbase = (size_t)i0 * GN + lane * 8;

    i32x4 ra[6], rb[6];
    auto issue = [&](int c, int jb) {
        const int* rp = adj + adjbase + (size_t)(c * 4 + wave) * GN + jb;
        ra[c % 6] = ((const i32x4*)rp)[0];
        rb[c % 6] = ((const i32x4*)rp)[1];
    };
    auto pack = [&](int c, int bufsel) {
        const i32x4 va = ra[c % 6], vb = rb[c % 6];
        unsigned byte = 0;
        #pragma unroll
        for (int q = 0; q < 4; ++q) {
            byte |= (va[q] > 0 ? 1u : 0u) << q;
            byte |= (vb[q] > 0 ? 1u : 0u) << (4 + q);
        }
        mb[bufsel][(c * 4 + wave) * LSTRIDE + lane] = (unsigned char)byte;
    };

    f32x4 acc0 = {0,0,0,0}, acc1 = {0,0,0,0}, acc2 = {0,0,0,0}, acc3 = {0,0,0,0};
    f32x4 acc4 = {0,0,0,0};             // row-sum via ones-MFMA
    bf16x8 ones;
    #pragma unroll
    for (int q = 0; q < 8; ++q) ones[q] = (short)0x3F80;

    // tile t processes columns js(t) = js0 + 8*(NTILE-1-t)  (descending)
    const int jb0 = (js0 + 8 * (NTILE - 1)) * JCH;

    // ---- prologue: stage tile 0 -> mb[0], lag-5 ring ----
    #pragma unroll
    for (int c = 0; c < 16; ++c) {
        issue(c, jb0);
        if (c >= 5) pack(c - 5, 0);
    }
    pack(11, 0); pack(12, 0); pack(13, 0); pack(14, 0); pack(15, 0);
    __syncthreads();

    // preload operands for tile 0, col-iter 0
    f32x4 dv0 = *(const f32x4*)(d_arr + jb0 + quad * 8);
    f32x4 dv1 = *(const f32x4*)(d_arr + jb0 + quad * 8 + 4);
    const ushort* bb0 = WhTp + ((size_t)(jb0 >> 3) + quad) * 512;
    bf16x8 b0 = *(const bf16x8*)(bb0 + ( 0 + lq) * 8);
    bf16x8 b1 = *(const bf16x8*)(bb0 + (16 + lq) * 8);
    bf16x8 b2 = *(const bf16x8*)(bb0 + (32 + lq) * 8);
    bf16x8 b3 = *(const bf16x8*)(bb0 + (48 + lq) * 8);

    #pragma unroll 1
    for (int t = 0; t < NTILE; ++t) {
        const int jb   = (js0 + 8 * (NTILE - 1 - t)) * JCH;
        const int jbn  = jb - 8 * JCH;          // next tile (descending)
        const bool more = (t < NTILE - 1);
        const int buf  = t & 1, nbuf = buf ^ 1;

        #pragma unroll
        for (int it = 0; it < 16; ++it) {
            // 1) rolling operand prefetch (issued before this iter's adj:
            //    its vmcnt wait never drains younger adj loads)
            const int jtb = (it < 15) ? jb : (more ? jbn : jb);
            const int itn = (it < 15) ? (it + 1) : 0;
            const int jn  = jtb + itn * 32 + quad * 8;
            f32x4 ndv0 = *(const f32x4*)(d_arr + jn);
            f32x4 ndv1 = *(const f32x4*)(d_arr + jn + 4);
            const ushort* nb = WhTp + ((size_t)(jtb >> 3) + itn * 4 + quad) * 512;
            bf16x8 nb0 = *(const bf16x8*)(nb + ( 0 + lq) * 8);
            bf16x8 nb1 = *(const bf16x8*)(nb + (16 + lq) * 8);
            bf16x8 nb2 = *(const bf16x8*)(nb + (32 + lq) * 8);
            bf16x8 nb3 = *(const bf16x8*)(nb + (48 + lq) * 8);
            // 2) issue next-tile adj chunk into the 6-deep ring
            if (more) issue(it, jbn);
            // 3) pack chunk it-5 (chunks it-4..it stay in flight: ~5 iter
            //    bodies ~1000-1250 cy of latency cover)
            if (more && it >= 5) pack(it - 5, nbuf);
            // 4) compute col-iter it
            unsigned bw = *(const unsigned*)(&mb[buf][li * LSTRIDE + it * 4]);
            const unsigned m8 = (bw >> (quad * 8)) & 0xffu;
            float w[8];
            #pragma unroll
            for (int q = 0; q < 4; ++q) {
                float a0 = fmaxf(dv0[q] + k1, fmaf(SLOPE, dv0[q], k2));
                float v0 = __expf(a0);
                w[q] = ((m8 >> q) & 1u) ? v0 : 0.f;
                float a1 = fmaxf(dv1[q] + k1, fmaf(SLOPE, dv1[q], k2));
                float v1 = __expf(a1);
                w[4 + q] = ((m8 >> (4 + q)) & 1u) ? v1 : 0.f;
            }
            union { bf16x8 v; __hip_bfloat162 h[4]; } af;
            #pragma unroll
            for (int q = 0; q < 4; ++q)
                af.h[q] = __float22bfloat162_rn(make_float2(w[2 * q], w[2 * q + 1]));
            acc0 = __builtin_amdgcn_mfma_f32_16x16x32_bf16(af.v, b0, acc0, 0, 0, 0);
            acc1 = __builtin_amdgcn_mfma_f32_16x16x32_bf16(af.v, b1, acc1, 0, 0, 0);
            acc2 = __builtin_amdgcn_mfma_f32_16x16x32_bf16(af.v, b2, acc2, 0, 0, 0);
            acc3 = __builtin_amdgcn_mfma_f32_16x16x32_bf16(af.v, b3, acc3, 0, 0, 0);
            acc4 = __builtin_amdgcn_mfma_f32_16x16x32_bf16(af.v, ones, acc4, 0, 0, 0);
            dv0 = ndv0; dv1 = ndv1; b0 = nb0; b1 = nb1; b2 = nb2; b3 = nb3;
        }
        if (more) {
            pack(11, nbuf); pack(12, nbuf); pack(13, nbuf);
            pack(14, nbuf); pack(15, nbuf);
        }
        __syncthreads();
    }

    // epilogue: C/D col=lq, row=quad*4+r; acc4 holds row sums in every col
    const int orow = i0 + wave * 16 + quad * 4;
    if (lq == 0) {
        #pragma unroll
        for (int r = 0; r < 4; ++r) atomicAdd(&lsum[orow + r], acc4[r]);
    }
    #pragma unroll
    for (int r = 0; r < 4; ++r) {
        atomicAdd(&accum[(size_t)(orow + r) * ODIM +  0 + lq], acc0[r]);
        atomicAdd(&accum[(size_t)(orow + r) * ODIM + 16 + lq], acc1[r]);
        atomicAdd(&accum[(size_t)(orow + r) * ODIM + 32 + lq], acc2[r]);
        atomicAdd(&accum[(size_t)(orow + r) * ODIM + 48 + lq], acc3[r]);
    }
}

// Kernel 3: out = (accum / lsum), dtype per flag
extern "C" __global__ __launch_bounds__(256)
void gat_final(const float* __restrict__ accum, const float* __restrict__ lsum,
               const int* __restrict__ flag, void* __restrict__ out)
{
    const int idx = blockIdx.x * 256 + threadIdx.x;
    const float v = accum[idx] / lsum[idx >> 6];
    if (*flag) ((float*)out)[idx] = v;
    else       ((ushort*)out)[idx] = f2bf(v);
}

extern "C" void kernel_launch(void* const* d_in, const int* in_sizes, int n_in,
                              void* d_out, int out_size, void* d_ws, size_t ws_size,
                              hipStream_t stream)
{
    const void* x     = d_in[0];
    const int*  adj   = (const int*)d_in[1];
    const void* W     = d_in[2];
    const void* a_src = d_in[3];
    const void* a_dst = d_in[4];

    char* ws = (char*)d_ws;
    size_t off = 0;
    int* dmax_bits = (int*)(ws + off);  off += 128;
    int* dflag = (int*)(ws + off);      off += 128;
    size_t zero_bytes = off;                                               // 256 B only
    float* accum = (float*)(ws + off);  off += (size_t)GN * ODIM * 4;      // 2 MB (proj zeroes)
    float* lsum  = (float*)(ws + off);  off += (size_t)GN * 4;             // 32 KB (proj zeroes)
    float* s_arr = (float*)(ws + off);  off += (size_t)GN * 4;
    float* d_arr = (float*)(ws + off);  off += (size_t)GN * 4;
    ushort* WhTp = (ushort*)(ws + off); off += (size_t)ODIM * GN * 2;      // 1 MB

    hipMemsetAsync(ws, 0, zero_bytes, stream);
    gat_proj<<<GN / 64, 256, 0, stream>>>(x, W, a_src, a_dst,
                                          WhTp, s_arr, d_arr, dmax_bits, dflag,
                                          accum, lsum);
    gat_attn<<<1024, 256, 0, stream>>>(adj, WhTp, s_arr, d_arr,
                                       dmax_bits, accum, lsum);
    gat_final<<<GN * ODIM / 256, 256, 0, stream>>>(accum, lsum, dflag, d_out);
}

// Round 12
// 424.074 us; speedup vs baseline: 1.0285x; 1.0285x over previous
//
#include <hip/hip_runtime.h>
#include <hip/hip_bf16.h>

#define GN 8192
#define IN_DIM 512
#define ODIM 64
#define SLOPE 0.2f
#define JSPLIT 16
#define JCH (GN / JSPLIT)      // 512 cols per tile
#define LSTRIDE 68             // LDS mask row stride bytes (17 words -> conflict-free)
#define NTILE 4                // tiles per block (js0 + 4t, traversed descending)

typedef __attribute__((ext_vector_type(4))) float  f32x4;
typedef __attribute__((ext_vector_type(4))) int    i32x4;
typedef __attribute__((ext_vector_type(8))) short  bf16x8;
typedef __attribute__((ext_vector_type(4))) unsigned short u16x4;

static __device__ __forceinline__ float bf2f(unsigned short u) {
    return __uint_as_float(((unsigned)u) << 16);
}
static __device__ __forceinline__ unsigned short f2bf(float f) {
    union { float f; unsigned u; } c; c.f = f;
    unsigned b = c.u;
    return (unsigned short)((b + 0x7fffu + ((b >> 16) & 1u)) >> 16);  // RNE
}

// load 8 contiguous elements as bf16x8, from either wire dtype
static __device__ __forceinline__ bf16x8 load8(const void* p, size_t off, int f32) {
    if (f32) {
        f32x4 lo = *(const f32x4*)((const float*)p + off);
        f32x4 hi = *(const f32x4*)((const float*)p + off + 4);
        bf16x8 r;
        #pragma unroll
        for (int q = 0; q < 4; ++q) {
            r[q]     = (short)f2bf(lo[q]);
            r[4 + q] = (short)f2bf(hi[q]);
        }
        return r;
    }
    return *(const bf16x8*)((const ushort*)p + off);
}

// Kernel 1 (MFMA GEMM): Wh = x@W^T. Epilogue writes WhTp in B-operand-native
// layout (16B unit U(jblk,n) = Wh[jblk*8+0..7][n]); s, d, dmax, dflag; zero-
// inits accum/lsum (kernel boundary orders it before gat_attn's atomics).
extern "C" __global__ __launch_bounds__(256)
void gat_proj(const void* __restrict__ x_, const void* __restrict__ W_,
              const void* __restrict__ as_, const void* __restrict__ ad_,
              ushort* __restrict__ WhTp, float* __restrict__ s_arr,
              float* __restrict__ d_arr, int* __restrict__ dmax_bits,
              int* __restrict__ dflag, float* __restrict__ accum,
              float* __restrict__ lsum)
{
    {
        f32x4 z = {0.f, 0.f, 0.f, 0.f};
        f32x4* ap = (f32x4*)(accum + (size_t)blockIdx.x * 4096);
        #pragma unroll
        for (int k = 0; k < 4; ++k) ap[k * 256 + threadIdx.x] = z;
        if (threadIdx.x < 64) lsum[blockIdx.x * 64 + threadIdx.x] = 0.f;
    }
    const int wave = threadIdx.x >> 6;
    const int lane = threadIdx.x & 63;
    unsigned xw = ((const unsigned*)x_)[lane];
    unsigned ef = (xw >> 23) & 0xffu;
    unsigned long long vt = __ballot(ef > 60u && ef < 180u);
    const int f32 = (__popcll(vt) >= 32) ? 1 : 0;
    if (blockIdx.x == 0 && threadIdx.x == 0) *dflag = f32;

    const int quad = lane >> 4;
    const int lq   = lane & 15;
    const int i0   = blockIdx.x * 64 + wave * 16;

    f32x4 acc[4] = {{0,0,0,0},{0,0,0,0},{0,0,0,0},{0,0,0,0}};
    const size_t arow = (size_t)(i0 + lq) * IN_DIM;
    #pragma unroll 2
    for (int k0 = 0; k0 < IN_DIM; k0 += 32) {
        const int kk = k0 + quad * 8;
        bf16x8 a  = load8(x_, arow + kk, f32);
        bf16x8 b0 = load8(W_, (size_t)( 0 + lq) * IN_DIM + kk, f32);
        bf16x8 b1 = load8(W_, (size_t)(16 + lq) * IN_DIM + kk, f32);
        bf16x8 b2 = load8(W_, (size_t)(32 + lq) * IN_DIM + kk, f32);
        bf16x8 b3 = load8(W_, (size_t)(48 + lq) * IN_DIM + kk, f32);
        acc[0] = __builtin_amdgcn_mfma_f32_16x16x32_bf16(a, b0, acc[0], 0, 0, 0);
        acc[1] = __builtin_amdgcn_mfma_f32_16x16x32_bf16(a, b1, acc[1], 0, 0, 0);
        acc[2] = __builtin_amdgcn_mfma_f32_16x16x32_bf16(a, b2, acc[2], 0, 0, 0);
        acc[3] = __builtin_amdgcn_mfma_f32_16x16x32_bf16(a, b3, acc[3], 0, 0, 0);
    }
    float av_s[4], av_d[4];
    #pragma unroll
    for (int t = 0; t < 4; ++t) {
        const int n = t * 16 + lq;
        av_s[t] = f32 ? ((const float*)as_)[n] : bf2f(((const ushort*)as_)[n]);
        av_d[t] = f32 ? ((const float*)ad_)[n] : bf2f(((const ushort*)ad_)[n]);
    }
    #pragma unroll
    for (int t = 0; t < 4; ++t) {
        u16x4 pk;
        #pragma unroll
        for (int r = 0; r < 4; ++r) pk[r] = f2bf(acc[t][r]);
        const size_t hw = ((size_t)((i0 >> 3) + (quad >> 1)) * 64 + t * 16 + lq) * 8
                          + (quad & 1) * 4;
        *(u16x4*)(WhTp + hw) = pk;
    }
    float ps[4], pd[4];
    #pragma unroll
    for (int r = 0; r < 4; ++r) {
        float s = 0.f, d = 0.f;
        #pragma unroll
        for (int t = 0; t < 4; ++t) {
            s = fmaf(acc[t][r], av_s[t], s);
            d = fmaf(acc[t][r], av_d[t], d);
        }
        #pragma unroll
        for (int off = 1; off < 16; off <<= 1) {
            s += __shfl_xor(s, off);
            d += __shfl_xor(d, off);
        }
        ps[r] = s; pd[r] = d;
    }
    if (lq == 0) {
        float dmx = -1e30f;
        #pragma unroll
        for (int r = 0; r < 4; ++r) {
            s_arr[i0 + quad * 4 + r] = ps[r];
            d_arr[i0 + quad * 4 + r] = pd[r];
            dmx = fmaxf(dmx, pd[r]);
        }
        if (dmx > 0.f) atomicMax(dmax_bits, __float_as_int(dmx));
    }
}

// Kernel 2: fused attention = EXACT R10 shape (512 blocks = 128 ib x 4 js0,
// NTILE=4, descending tiles, reversed ib, default launch bounds) with the
// single isolated change vs R10: ring 6 / pack-lag 5 (~5 iter-bodies
// ~1100+ cy of latency cover vs ~900 cy HBM miss; R10's lag 4 was ~800,
// right at the edge). R11 conflated depth with a worse grid shape.
extern "C" __global__ __launch_bounds__(256)
void gat_attn(const int* __restrict__ adj, const ushort* __restrict__ WhTp,
              const float* __restrict__ s_arr, const float* __restrict__ d_arr,
              const int* __restrict__ dmax_bits,
              float* __restrict__ accum, float* __restrict__ lsum)
{
    __shared__ unsigned char mb[2][64 * LSTRIDE];
    const int b    = blockIdx.x;        // 0..511
    const int ib   = 127 - (b & 127);   // reversed: high rows first
    const int js0  = b >> 7;            // 0..3
    const int wave = threadIdx.x >> 6;
    const int lane = threadIdx.x & 63;
    const int quad = lane >> 4;
    const int lq   = lane & 15;
    const int i0   = ib * 64;
    const int li   = wave * 16 + lq;
    const int i    = i0 + li;
    const float dmax = __int_as_float(*dmax_bits);
    const float si = s_arr[i];
    const float tbv = si + dmax;
    const float mi = fmaxf(tbv, SLOPE * tbv);   // row-logit upper bound
    const float k1 = si - mi;                   // arg = max(dj+k1, 0.2dj+k2)
    const float k2 = SLOPE * si - mi;

    const size_t adjbase = (size_t)i0 * GN + lane * 8;

    i32x4 ra[6], rb[6];
    auto issue = [&](int c, int jb) {
        const int* rp = adj + adjbase + (size_t)(c * 4 + wave) * GN + jb;
        ra[c % 6] = ((const i32x4*)rp)[0];
        rb[c % 6] = ((const i32x4*)rp)[1];
    };
    auto pack = [&](int c, int bufsel) {
        const i32x4 va = ra[c % 6], vb = rb[c % 6];
        unsigned byte = 0;
        #pragma unroll
        for (int q = 0; q < 4; ++q) {
            byte |= (va[q] > 0 ? 1u : 0u) << q;
            byte |= (vb[q] > 0 ? 1u : 0u) << (4 + q);
        }
        mb[bufsel][(c * 4 + wave) * LSTRIDE + lane] = (unsigned char)byte;
    };

    f32x4 acc0 = {0,0,0,0}, acc1 = {0,0,0,0}, acc2 = {0,0,0,0}, acc3 = {0,0,0,0};
    f32x4 acc4 = {0,0,0,0};             // row-sum via ones-MFMA
    bf16x8 ones;
    #pragma unroll
    for (int q = 0; q < 8; ++q) ones[q] = (short)0x3F80;

    // tile t processes columns js(t) = js0 + 4*(NTILE-1-t)  (descending)
    const int jb0 = (js0 + 4 * (NTILE - 1)) * JCH;

    // ---- prologue: stage tile 0 -> mb[0], lag-5 ring ----
    #pragma unroll
    for (int c = 0; c < 16; ++c) {
        issue(c, jb0);
        if (c >= 5) pack(c - 5, 0);
    }
    pack(11, 0); pack(12, 0); pack(13, 0); pack(14, 0); pack(15, 0);
    __syncthreads();

    // preload operands for tile 0, col-iter 0
    f32x4 dv0 = *(const f32x4*)(d_arr + jb0 + quad * 8);
    f32x4 dv1 = *(const f32x4*)(d_arr + jb0 + quad * 8 + 4);
    const ushort* bb0 = WhTp + ((size_t)(jb0 >> 3) + quad) * 512;
    bf16x8 b0 = *(const bf16x8*)(bb0 + ( 0 + lq) * 8);
    bf16x8 b1 = *(const bf16x8*)(bb0 + (16 + lq) * 8);
    bf16x8 b2 = *(const bf16x8*)(bb0 + (32 + lq) * 8);
    bf16x8 b3 = *(const bf16x8*)(bb0 + (48 + lq) * 8);

    #pragma unroll 1
    for (int t = 0; t < NTILE; ++t) {
        const int jb   = (js0 + 4 * (NTILE - 1 - t)) * JCH;
        const int jbn  = jb - 4 * JCH;          // next tile (descending)
        const bool more = (t < NTILE - 1);
        const int buf  = t & 1, nbuf = buf ^ 1;

        #pragma unroll
        for (int it = 0; it < 16; ++it) {
            // 1) rolling operand prefetch (issued before this iter's adj:
            //    its vmcnt wait never drains younger adj loads)
            const int jtb = (it < 15) ? jb : (more ? jbn : jb);
            const int itn = (it < 15) ? (it + 1) : 0;
            const int jn  = jtb + itn * 32 + quad * 8;
            f32x4 ndv0 = *(const f32x4*)(d_arr + jn);
            f32x4 ndv1 = *(const f32x4*)(d_arr + jn + 4);
            const ushort* nb = WhTp + ((size_t)(jtb >> 3) + itn * 4 + quad) * 512;
            bf16x8 nb0 = *(const bf16x8*)(nb + ( 0 + lq) * 8);
            bf16x8 nb1 = *(const bf16x8*)(nb + (16 + lq) * 8);
            bf16x8 nb2 = *(const bf16x8*)(nb + (32 + lq) * 8);
            bf16x8 nb3 = *(const bf16x8*)(nb + (48 + lq) * 8);
            // 2) issue next-tile adj chunk into the 6-deep ring
            if (more) issue(it, jbn);
            // 3) pack chunk it-5 (chunks it-4..it stay in flight: ~5 iter
            //    bodies ~1100+ cy of latency cover)
            if (more && it >= 5) pack(it - 5, nbuf);
            // 4) compute col-iter it
            unsigned bw = *(const unsigned*)(&mb[buf][li * LSTRIDE + it * 4]);
            const unsigned m8 = (bw >> (quad * 8)) & 0xffu;
            float w[8];
            #pragma unroll
            for (int q = 0; q < 4; ++q) {
                float a0 = fmaxf(dv0[q] + k1, fmaf(SLOPE, dv0[q], k2));
                float v0 = __expf(a0);
                w[q] = ((m8 >> q) & 1u) ? v0 : 0.f;
                float a1 = fmaxf(dv1[q] + k1, fmaf(SLOPE, dv1[q], k2));
                float v1 = __expf(a1);
                w[4 + q] = ((m8 >> (4 + q)) & 1u) ? v1 : 0.f;
            }
            union { bf16x8 v; __hip_bfloat162 h[4]; } af;
            #pragma unroll
            for (int q = 0; q < 4; ++q)
                af.h[q] = __float22bfloat162_rn(make_float2(w[2 * q], w[2 * q + 1]));
            acc0 = __builtin_amdgcn_mfma_f32_16x16x32_bf16(af.v, b0, acc0, 0, 0, 0);
            acc1 = __builtin_amdgcn_mfma_f32_16x16x32_bf16(af.v, b1, acc1, 0, 0, 0);
            acc2 = __builtin_amdgcn_mfma_f32_16x16x32_bf16(af.v, b2, acc2, 0, 0, 0);
            acc3 = __builtin_amdgcn_mfma_f32_16x16x32_bf16(af.v, b3, acc3, 0, 0, 0);
            acc4 = __builtin_amdgcn_mfma_f32_16x16x32_bf16(af.v, ones, acc4, 0, 0, 0);
            dv0 = ndv0; dv1 = ndv1; b0 = nb0; b1 = nb1; b2 = nb2; b3 = nb3;
        }
        if (more) {
            pack(11, nbuf); pack(12, nbuf); pack(13, nbuf);
            pack(14, nbuf); pack(15, nbuf);
        }
        __syncthreads();
    }

    // epilogue: C/D col=lq, row=quad*4+r; acc4 holds row sums in every col
    const int orow = i0 + wave * 16 + quad * 4;
    if (lq == 0) {
        #pragma unroll
        for (int r = 0; r < 4; ++r) atomicAdd(&lsum[orow + r], acc4[r]);
    }
    #pragma unroll
    for (int r = 0; r < 4; ++r) {
        atomicAdd(&accum[(size_t)(orow + r) * ODIM +  0 + lq], acc0[r]);
        atomicAdd(&accum[(size_t)(orow + r) * ODIM + 16 + lq], acc1[r]);
        atomicAdd(&accum[(size_t)(orow + r) * ODIM + 32 + lq], acc2[r]);
        atomicAdd(&accum[(size_t)(orow + r) * ODIM + 48 + lq], acc3[r]);
    }
}

// Kernel 3: out = (accum / lsum), dtype per flag
extern "C" __global__ __launch_bounds__(256)
void gat_final(const float* __restrict__ accum, const float* __restrict__ lsum,
               const int* __restrict__ flag, void* __restrict__ out)
{
    const int idx = blockIdx.x * 256 + threadIdx.x;
    const float v = accum[idx] / lsum[idx >> 6];
    if (*flag) ((float*)out)[idx] = v;
    else       ((ushort*)out)[idx] = f2bf(v);
}

extern "C" void kernel_launch(void* const* d_in, const int* in_sizes, int n_in,
                              void* d_out, int out_size, void* d_ws, size_t ws_size,
                              hipStream_t stream)
{
    const void* x     = d_in[0];
    const int*  adj   = (const int*)d_in[1];
    const void* W     = d_in[2];
    const void* a_src = d_in[3];
    const void* a_dst = d_in[4];

    char* ws = (char*)d_ws;
    size_t off = 0;
    int* dmax_bits = (int*)(ws + off);  off += 128;
    int* dflag = (int*)(ws + off);      off += 128;
    size_t zero_bytes = off;                                               // 256 B only
    float* accum = (float*)(ws + off);  off += (size_t)GN * ODIM * 4;      // 2 MB (proj zeroes)
    float* lsum  = (float*)(ws + off);  off += (size_t)GN * 4;             // 32 KB (proj zeroes)
    float* s_arr = (float*)(ws + off);  off += (size_t)GN * 4;
    float* d_arr = (float*)(ws + off);  off += (size_t)GN * 4;
    ushort* WhTp = (ushort*)(ws + off); off += (size_t)ODIM * GN * 2;      // 1 MB

    hipMemsetAsync(ws, 0, zero_bytes, stream);
    gat_proj<<<GN / 64, 256, 0, stream>>>(x, W, a_src, a_dst,
                                          WhTp, s_arr, d_arr, dmax_bits, dflag,
                                          accum, lsum);
    gat_attn<<<512, 256, 0, stream>>>(adj, WhTp, s_arr, d_arr,
                                      dmax_bits, accum, lsum);
    gat_final<<<GN * ODIM / 256, 256, 0, stream>>>(accum, lsum, dflag, d_out);
}